// Round 3
// baseline (1646.067 us; speedup 1.0000x reference)
//
#include <hip/hip_runtime.h>
#include <hip/hip_bf16.h>

typedef unsigned short u16;
typedef unsigned int u32;
// MFMA operand type per guide §3 (compile-verified form on gfx950):
// 8 bf16 values bit-carried in an ext_vector of short.
typedef __attribute__((ext_vector_type(8))) short bf16x8;
typedef __attribute__((ext_vector_type(4))) float f32x4;

#define DEV static __device__ __forceinline__

// fp32 -> bf16, round-to-nearest-even
DEV u16 f2b(float f) {
  union { float f; u32 u; } v; v.f = f;
  return (u16)((v.u + 0x7fffu + ((v.u >> 16) & 1u)) >> 16);
}

// async global->LDS, 16B per lane. LDS dest must be linear in lane order.
DEV void gload16(const void* g, void* l) {
  __builtin_amdgcn_global_load_lds(
      (const __attribute__((address_space(1))) u32*)g,
      (__attribute__((address_space(3))) u32*)l, 16, 0, 0);
}

// ---------------------------------------------------------------- converts
__global__ __launch_bounds__(256) void cvt_bf16(const float* __restrict__ s,
                                                u16* __restrict__ d) {
  const long i = ((long)blockIdx.x * 256 + threadIdx.x) * 4;
  const float4 v = *(const float4*)&s[i];
  ushort4 o;
  o.x = f2b(v.x); o.y = f2b(v.y); o.z = f2b(v.z); o.w = f2b(v.w);
  *(ushort4*)&d[i] = o;
}

// src [bz][R][C] fp32 -> dst [bz][C][R] bf16 (strides in elements)
__global__ __launch_bounds__(256) void tpose_bf16(const float* __restrict__ src,
                                                  u16* __restrict__ dst, int R,
                                                  int C, long sStride,
                                                  long dStride) {
  __shared__ float tl[32][33];
  const float* s = src + (long)blockIdx.z * sStride;
  u16* d = dst + (long)blockIdx.z * dStride;
  const int c0 = blockIdx.x * 32, r0 = blockIdx.y * 32;
  const int tx = threadIdx.x, ty = threadIdx.y;  // (32,8)
#pragma unroll
  for (int k = 0; k < 4; k++)
    tl[ty + k * 8][tx] = s[(long)(r0 + ty + k * 8) * C + c0 + tx];
  __syncthreads();
#pragma unroll
  for (int k = 0; k < 4; k++)
    d[(long)(c0 + ty + k * 8) * R + r0 + tx] = f2b(tl[tx][ty + k * 8]);
}

// ---------------------------------------------------------------- GEMM
// C[row][col] = sum_k A[row][k] * Bt[col][k]   (A row-major, B transposed)
// 128x128 tile, BK=32, 4 waves (2x2), 4x4 x mfma_f32_16x16x32_bf16 per wave.
enum { EQKV, EPROJ, EFF1, EFF2, EFF2I };

template <int EPI>
__global__ __launch_bounds__(256, 2) void gemm_bt(
    const u16* __restrict__ A, const u16* __restrict__ Bt, int K, int lda,
    int ldb, const float* __restrict__ c0, const float* __restrict__ c1,
    const float* __restrict__ c2, const float* __restrict__ aux,
    float* __restrict__ fout, u16* __restrict__ o0, u16* __restrict__ o1,
    u16* __restrict__ o2, int nexp) {
  __shared__ u16 As[4096], Bs[4096];
  if constexpr (EPI == EFF2 || EPI == EFF2I) {  // K-split over grid.z
    const int z = blockIdx.z;
    A += (long)z * 2048;
    Bt += (long)z * 2048;
    fout += (long)z * 4194304;  // 4096*1024 fp32 partial buffer per z
  }
  const int tid = threadIdx.x;
  const int m0 = blockIdx.y * 128, n0 = blockIdx.x * 128;
  const int w = tid >> 6, l = tid & 63;
  const int wm = (w >> 1) * 64, wn = (w & 1) * 64;
  const int lr = l & 15, lh = l >> 4;
  f32x4 acc[4][4] = {};
  const u16* Ag = A + (long)(m0 + (tid >> 2)) * lda + (tid & 3) * 8;
  const u16* Bg = Bt + (long)(n0 + (tid >> 2)) * ldb + (tid & 3) * 8;
  const long rsA = (long)64 * lda, rsB = (long)64 * ldb;
  for (int kt = 0; kt < K; kt += 32) {
    __syncthreads();
    gload16(Ag, As + tid * 8);
    gload16(Ag + rsA, As + tid * 8 + 2048);
    gload16(Bg, Bs + tid * 8);
    gload16(Bg + rsB, Bs + tid * 8 + 2048);
    Ag += 32; Bg += 32;
    __syncthreads();
    bf16x8 af[4], bfr[4];
#pragma unroll
    for (int i = 0; i < 4; i++)
      af[i] = *(const bf16x8*)&As[(wm + i * 16 + lr) * 32 + lh * 8];
#pragma unroll
    for (int j = 0; j < 4; j++)
      bfr[j] = *(const bf16x8*)&Bs[(wn + j * 16 + lr) * 32 + lh * 8];
#pragma unroll
    for (int i = 0; i < 4; i++)
#pragma unroll
      for (int j = 0; j < 4; j++)
        acc[i][j] = __builtin_amdgcn_mfma_f32_16x16x32_bf16(af[i], bfr[j],
                                                            acc[i][j], 0, 0, 0);
  }
  // epilogue: elem (i,j,r) -> row = m0+wm+i*16+lh*4+r, col = n0+wn+j*16+lr
#pragma unroll
  for (int j = 0; j < 4; j++) {
    const int col = n0 + wn + j * 16 + lr;
#pragma unroll
    for (int i = 0; i < 4; i++)
#pragma unroll
      for (int r = 0; r < 4; r++) {
        const int row = m0 + wm + i * 16 + lh * 4 + r;
        float v = acc[i][j][r];
        if constexpr (EPI == EQKV) {
          const int which = col >> 10, hd = col & 1023;
          const float vb =
              v + ((which == 0) ? c0 : (which == 1) ? c1 : c2)[hd];
          const int b = row >> 10, s = row & 1023;
          const int h = hd >> 6, d = hd & 63;
          const long bh = b * 16 + h;
          if (which == 0)
            o0[(bh * 1024 + s) * 64 + d] = f2b(vb * 0.125f);  // q, pre-scaled
          else if (which == 1)
            o1[(bh * 1024 + s) * 64 + d] = f2b(vb);           // k
          else
            o2[bh * 65536 + (long)d * 1024 + s] = f2b(vb);    // v transposed
        } else if constexpr (EPI == EPROJ) {
          const long idx = (long)row * 1024 + col;
          fout[idx] = v + c0[col] + aux[idx];  // + bp + x residual
        } else if constexpr (EPI == EFF1) {
          const float t = v + c0[col];
          o0[(long)row * 4096 + col] = f2b(t > 0.f ? t : 0.f);  // relu
        } else {  // EFF2 / EFF2I
          float vb = v;
          if (blockIdx.z == 0) vb += c0[col];  // b2 once per expert
          const float t = aux[row * 8 + nexp] * vb;  // probs weight
          const long idx = (long)row * 1024 + col;
          if constexpr (EPI == EFF2I)
            fout[idx] = t;
          else
            fout[idx] = fout[idx] + t;
        }
      }
  }
}

// ---------------------------------------------------------------- attention
// grid (S/64, B*H), 4 waves/block, 16 q-rows per wave, KT=32 causal tiles.
__global__ __launch_bounds__(256) void attn_fwd(const u16* __restrict__ Qb,
                                                const u16* __restrict__ Kb,
                                                const u16* __restrict__ Vt,
                                                u16* __restrict__ Cat) {
  __shared__ u16 Pl[4][512];  // per-wave 16x32 P staging
  const int tid = threadIdx.x;
  const int w = tid >> 6, l = tid & 63;
  const int lr = l & 15, lh = l >> 4;
  const int bh = blockIdx.y;
  const int q0 = blockIdx.x * 64 + w * 16;
  const u16* Qp = Qb + (long)bh * 65536;
  const u16* Kp = Kb + (long)bh * 65536;
  const u16* Vp = Vt + (long)bh * 65536;  // [64][1024]
  const bf16x8 qf0 = *(const bf16x8*)&Qp[(q0 + lr) * 64 + lh * 8];
  const bf16x8 qf1 = *(const bf16x8*)&Qp[(q0 + lr) * 64 + 32 + lh * 8];
  f32x4 o[4] = {};
  float mrow[4] = {-1e30f, -1e30f, -1e30f, -1e30f};
  float ssum[4] = {0.f, 0.f, 0.f, 0.f};
  u16* P = Pl[w];
  const int nkt = (q0 + 15) / 32 + 1;
  for (int kt = 0; kt < nkt; kt++) {
    const int t0 = kt * 32;
    f32x4 sc[2];
#pragma unroll
    for (int ts = 0; ts < 2; ts++) {
      const bf16x8 kf0 =
          *(const bf16x8*)&Kp[(t0 + ts * 16 + lr) * 64 + lh * 8];
      const bf16x8 kf1 =
          *(const bf16x8*)&Kp[(t0 + ts * 16 + lr) * 64 + 32 + lh * 8];
      f32x4 c = {};
      c = __builtin_amdgcn_mfma_f32_16x16x32_bf16(qf0, kf0, c, 0, 0, 0);
      c = __builtin_amdgcn_mfma_f32_16x16x32_bf16(qf1, kf1, c, 0, 0, 0);
      sc[ts] = c;
    }
#pragma unroll
    for (int ts = 0; ts < 2; ts++) {
      const int tcol = t0 + ts * 16 + lr;
#pragma unroll
      for (int i = 0; i < 4; i++)
        if (tcol > q0 + lh * 4 + i) sc[ts][i] = -1e30f;  // causal
    }
    float mt[4], mnew[4], scl[4], ps[4];
#pragma unroll
    for (int i = 0; i < 4; i++) mt[i] = fmaxf(sc[0][i], sc[1][i]);
#pragma unroll
    for (int d = 1; d < 16; d <<= 1)
#pragma unroll
      for (int i = 0; i < 4; i++) mt[i] = fmaxf(mt[i], __shfl_xor(mt[i], d));
#pragma unroll
    for (int i = 0; i < 4; i++) {
      mnew[i] = fmaxf(mrow[i], mt[i]);
      scl[i] = __expf(mrow[i] - mnew[i]);
      mrow[i] = mnew[i];
      ps[i] = 0.f;
    }
#pragma unroll
    for (int ts = 0; ts < 2; ts++)
#pragma unroll
      for (int i = 0; i < 4; i++) {
        const float p = __expf(sc[ts][i] - mnew[i]);
        ps[i] += p;
        P[(lh * 4 + i) * 32 + ts * 16 + lr] = f2b(p);  // transpose via LDS
      }
#pragma unroll
    for (int d = 1; d < 16; d <<= 1)
#pragma unroll
      for (int i = 0; i < 4; i++) ps[i] += __shfl_xor(ps[i], d);
#pragma unroll
    for (int i = 0; i < 4; i++) ssum[i] = ssum[i] * scl[i] + ps[i];
#pragma unroll
    for (int dt = 0; dt < 4; dt++)
#pragma unroll
      for (int i = 0; i < 4; i++) o[dt][i] *= scl[i];
    const bf16x8 pf = *(const bf16x8*)&P[lr * 32 + lh * 8];
#pragma unroll
    for (int dt = 0; dt < 4; dt++) {
      const bf16x8 vf =
          *(const bf16x8*)&Vp[(dt * 16 + lr) * 1024 + t0 + lh * 8];
      o[dt] = __builtin_amdgcn_mfma_f32_16x16x32_bf16(pf, vf, o[dt], 0, 0, 0);
    }
  }
  const int b = bh >> 4, h = bh & 15;
#pragma unroll
  for (int dt = 0; dt < 4; dt++)
#pragma unroll
    for (int i = 0; i < 4; i++) {
      const int q = q0 + lh * 4 + i;
      Cat[((long)(b * 1024 + q)) * 1024 + h * 64 + dt * 16 + lr] =
          f2b(o[dt][i] / ssum[i]);
    }
}

// ---------------------------------------------------------------- LN kernels
DEV float wred(float v) {
#pragma unroll
  for (int d = 1; d < 64; d <<= 1) v += __shfl_xor(v, d);
  return v;
}

__global__ __launch_bounds__(256) void ln1_router(
    const float* __restrict__ in, const float* __restrict__ g,
    const float* __restrict__ bb, const float* __restrict__ wr,
    const float* __restrict__ br, u16* __restrict__ h,
    float* __restrict__ probs) {
  __shared__ float rs[4], rs2[4], rp[4][8];
  const int row = blockIdx.x, t = threadIdx.x;
  const int w = t >> 6, l = t & 63;
  const float4 v = *(const float4*)&in[(long)row * 1024 + t * 4];
  float s = v.x + v.y + v.z + v.w;
  float s2 = v.x * v.x + v.y * v.y + v.z * v.z + v.w * v.w;
  s = wred(s);
  s2 = wred(s2);
  if (l == 0) { rs[w] = s; rs2[w] = s2; }
  __syncthreads();
  const float S = rs[0] + rs[1] + rs[2] + rs[3];
  const float S2 = rs2[0] + rs2[1] + rs2[2] + rs2[3];
  const float mean = S * (1.f / 1024.f);
  const float var = S2 * (1.f / 1024.f) - mean * mean;
  const float rr = rsqrtf(var + 1e-5f);
  const float4 gv = *(const float4*)&g[t * 4];
  const float4 bv = *(const float4*)&bb[t * 4];
  float hv[4];
  hv[0] = (v.x - mean) * rr * gv.x + bv.x;
  hv[1] = (v.y - mean) * rr * gv.y + bv.y;
  hv[2] = (v.z - mean) * rr * gv.z + bv.z;
  hv[3] = (v.w - mean) * rr * gv.w + bv.w;
  ushort4 hb;
  hb.x = f2b(hv[0]); hb.y = f2b(hv[1]); hb.z = f2b(hv[2]); hb.w = f2b(hv[3]);
  *(ushort4*)&h[(long)row * 1024 + t * 4] = hb;
  float pr[8] = {};
  const float* wrp = wr + t * 4 * 8;
#pragma unroll
  for (int e = 0; e < 4; e++)
#pragma unroll
    for (int j = 0; j < 8; j++) pr[j] += hv[e] * wrp[e * 8 + j];
#pragma unroll
  for (int j = 0; j < 8; j++) pr[j] = wred(pr[j]);
  if (l == 0)
#pragma unroll
    for (int j = 0; j < 8; j++) rp[w][j] = pr[j];
  __syncthreads();
  if (t == 0) {
    float lg[8], mx = -1e30f;
#pragma unroll
    for (int j = 0; j < 8; j++) {
      lg[j] = rp[0][j] + rp[1][j] + rp[2][j] + rp[3][j] + br[j];
      mx = fmaxf(mx, lg[j]);
    }
    float sm = 0.f;
#pragma unroll
    for (int j = 0; j < 8; j++) {
      lg[j] = __expf(lg[j] - mx);
      sm += lg[j];
    }
    const float inv = 1.f / sm;
#pragma unroll
    for (int j = 0; j < 8; j++) probs[row * 8 + j] = lg[j] * inv;
  }
}

// out = LN(in0 + in1 + xres)
__global__ __launch_bounds__(256) void ln2_kernel(
    const float* __restrict__ in0, const float* __restrict__ in1,
    const float* __restrict__ xres, const float* __restrict__ g,
    const float* __restrict__ bb, float* __restrict__ out) {
  __shared__ float rs[4], rs2[4];
  const int row = blockIdx.x, t = threadIdx.x;
  const int w = t >> 6, l = t & 63;
  const long base = (long)row * 1024 + t * 4;
  const float4 a = *(const float4*)&in0[base];
  const float4 b = *(const float4*)&in1[base];
  const float4 c = *(const float4*)&xres[base];
  float4 v;
  v.x = a.x + b.x + c.x; v.y = a.y + b.y + c.y;
  v.z = a.z + b.z + c.z; v.w = a.w + b.w + c.w;
  float s = v.x + v.y + v.z + v.w;
  float s2 = v.x * v.x + v.y * v.y + v.z * v.z + v.w * v.w;
  s = wred(s);
  s2 = wred(s2);
  if (l == 0) { rs[w] = s; rs2[w] = s2; }
  __syncthreads();
  const float S = rs[0] + rs[1] + rs[2] + rs[3];
  const float S2 = rs2[0] + rs2[1] + rs2[2] + rs2[3];
  const float mean = S * (1.f / 1024.f);
  const float var = S2 * (1.f / 1024.f) - mean * mean;
  const float rr = rsqrtf(var + 1e-5f);
  const float4 gv = *(const float4*)&g[t * 4];
  const float4 bv = *(const float4*)&bb[t * 4];
  float4 o;
  o.x = (v.x - mean) * rr * gv.x + bv.x;
  o.y = (v.y - mean) * rr * gv.y + bv.y;
  o.z = (v.z - mean) * rr * gv.z + bv.z;
  o.w = (v.w - mean) * rr * gv.w + bv.w;
  *(float4*)&out[base] = o;
}

// ---------------------------------------------------------------- launch
extern "C" void kernel_launch(void* const* d_in, const int* in_sizes, int n_in,
                              void* d_out, int out_size, void* d_ws,
                              size_t ws_size, hipStream_t stream) {
  const float* x = (const float*)d_in[0];
  const float* wq = (const float*)d_in[1];
  const float* bq = (const float*)d_in[2];
  const float* wk = (const float*)d_in[3];
  const float* bk = (const float*)d_in[4];
  const float* wv = (const float*)d_in[5];
  const float* bv = (const float*)d_in[6];
  const float* wp = (const float*)d_in[7];
  const float* bp = (const float*)d_in[8];
  const float* g1 = (const float*)d_in[9];
  const float* be1 = (const float*)d_in[10];
  const float* g2 = (const float*)d_in[11];
  const float* be2 = (const float*)d_in[12];
  const float* wr = (const float*)d_in[13];
  const float* br = (const float*)d_in[14];
  const float* w1 = (const float*)d_in[15];
  const float* b1 = (const float*)d_in[16];
  const float* w2 = (const float*)d_in[17];
  const float* b2 = (const float*)d_in[18];
  float* out = (float*)d_out;

  char* p = (char*)d_ws;
  auto alloc = [&](size_t bytes) {
    char* r = p;
    p += (bytes + 255) & ~(size_t)255;
    return r;
  };
  u16* xb = (u16*)alloc(8388608);        // x bf16 [4096][1024]
  u16* wqkvt = (u16*)alloc(6291456);     // [3072][1024] (q,k,v stacked)
  u16* wpt = (u16*)alloc(2097152);       // [1024][1024]
  u16* w1t = (u16*)alloc(67108864);      // [8][4096][1024]
  u16* w2t = (u16*)alloc(67108864);      // [8][1024][4096]
  u16* qb = (u16*)alloc(8388608);        // [64][1024][64], pre-scaled 1/8
  u16* kb = (u16*)alloc(8388608);        // [64][1024][64]
  u16* vt = (u16*)alloc(8388608);        // [64][64][1024]  (V^T)
  u16* cat = (u16*)alloc(8388608);       // [4096][1024]
  float* resid1 = (float*)alloc(16777216);
  u16* hb = (u16*)alloc(8388608);
  float* probs = (float*)alloc(131072);
  float* moe = (float*)alloc(33554432);  // 2 x [4096][1024] fp32 partials
  // mid [4096][4096] bf16 (32 MB) aliases {qb,kb,vt,cat}: those are dead
  // after EPROJ, and mid is first written after ln1_router. Saves 32 MB ws.
  u16* mid = qb;

  const dim3 tb(32, 8);
  cvt_bf16<<<4096, 256, 0, stream>>>(x, xb);
  tpose_bf16<<<dim3(2, 32, 16), tb, 0, stream>>>(wq, wqkvt, 1024, 64, 65536, 65536);
  tpose_bf16<<<dim3(2, 32, 16), tb, 0, stream>>>(wk, wqkvt + 1048576, 1024, 64, 65536, 65536);
  tpose_bf16<<<dim3(2, 32, 16), tb, 0, stream>>>(wv, wqkvt + 2097152, 1024, 64, 65536, 65536);
  tpose_bf16<<<dim3(32, 32, 1), tb, 0, stream>>>(wp, wpt, 1024, 1024, 0, 0);
  tpose_bf16<<<dim3(128, 32, 8), tb, 0, stream>>>(w1, w1t, 1024, 4096, 4194304, 4194304);
  tpose_bf16<<<dim3(32, 128, 8), tb, 0, stream>>>(w2, w2t, 4096, 1024, 4194304, 4194304);

  gemm_bt<EQKV><<<dim3(24, 32), 256, 0, stream>>>(
      xb, wqkvt, 1024, 1024, 1024, bq, bk, bv, nullptr, nullptr, qb, kb, vt, 0);
  attn_fwd<<<dim3(16, 64), 256, 0, stream>>>(qb, kb, vt, cat);
  gemm_bt<EPROJ><<<dim3(8, 32), 256, 0, stream>>>(
      cat, wpt, 1024, 1024, 1024, bp, nullptr, nullptr, x, resid1, nullptr,
      nullptr, nullptr, 0);
  ln1_router<<<4096, 256, 0, stream>>>(resid1, g1, be1, wr, br, hb, probs);
  for (int n = 0; n < 8; n++) {
    gemm_bt<EFF1><<<dim3(32, 32), 256, 0, stream>>>(
        hb, w1t + (long)n * 4194304, 1024, 1024, 1024, b1 + n * 4096, nullptr,
        nullptr, nullptr, nullptr, mid, nullptr, nullptr, n);
    if (n == 0)
      gemm_bt<EFF2I><<<dim3(8, 32, 2), 256, 0, stream>>>(
          mid, w2t + (long)n * 4194304, 2048, 4096, 4096, b2 + n * 1024,
          nullptr, nullptr, probs, moe, nullptr, nullptr, nullptr, n);
    else
      gemm_bt<EFF2><<<dim3(8, 32, 2), 256, 0, stream>>>(
          mid, w2t + (long)n * 4194304, 2048, 4096, 4096, b2 + n * 1024,
          nullptr, nullptr, probs, moe, nullptr, nullptr, nullptr, n);
  }
  ln2_kernel<<<4096, 256, 0, stream>>>(moe, moe + 4194304, x, g2, be2, out);
}

// Round 4
// 1524.988 us; speedup vs baseline: 1.0794x; 1.0794x over previous
//
#include <hip/hip_runtime.h>
#include <hip/hip_bf16.h>

typedef unsigned short u16;
typedef unsigned int u32;
typedef __attribute__((ext_vector_type(8))) short bf16x8;
typedef __attribute__((ext_vector_type(4))) float f32x4;

#define DEV static __device__ __forceinline__

// fp32 -> bf16, round-to-nearest-even
DEV u16 f2b(float f) {
  union { float f; u32 u; } v; v.f = f;
  return (u16)((v.u + 0x7fffu + ((v.u >> 16) & 1u)) >> 16);
}

// async global->LDS, 16B per lane. LDS dest linear in lane order (wave-uniform
// base + lane*16 — tid*8 u16 satisfies this).
DEV void gload16(const void* g, void* l) {
  __builtin_amdgcn_global_load_lds(
      (const __attribute__((address_space(1))) u32*)g,
      (__attribute__((address_space(3))) u32*)l, 16, 0, 0);
}

// ---------------------------------------------------------------- converts
__global__ __launch_bounds__(256) void cvt_bf16(const float* __restrict__ s,
                                                u16* __restrict__ d) {
  const long i = ((long)blockIdx.x * 256 + threadIdx.x) * 4;
  const float4 v = *(const float4*)&s[i];
  ushort4 o;
  o.x = f2b(v.x); o.y = f2b(v.y); o.z = f2b(v.z); o.w = f2b(v.w);
  *(ushort4*)&d[i] = o;
}

// src [bz][R][C] fp32 -> dst: elem [c][r] stored at dst + bz*dStride + c*ldd + r
__global__ __launch_bounds__(256) void tpose_bf16(const float* __restrict__ src,
                                                  u16* __restrict__ dst, int R,
                                                  int C, long sStride,
                                                  long dStride, long ldd) {
  __shared__ float tl[32][33];
  const float* s = src + (long)blockIdx.z * sStride;
  u16* d = dst + (long)blockIdx.z * dStride;
  const int c0 = blockIdx.x * 32, r0 = blockIdx.y * 32;
  const int tx = threadIdx.x, ty = threadIdx.y;  // (32,8)
#pragma unroll
  for (int k = 0; k < 4; k++)
    tl[ty + k * 8][tx] = s[(long)(r0 + ty + k * 8) * C + c0 + tx];
  __syncthreads();
#pragma unroll
  for (int k = 0; k < 4; k++)
    d[(long)(c0 + ty + k * 8) * ldd + r0 + tx] = f2b(tl[tx][ty + k * 8]);
}

// ---------------------------------------------------------------- GEMM
// C[row][col] = sum_k A[row][k] * Bt[col][k]   (A row-major, B^T row-major)
// 128x128 tile, BK=64, 4 waves (2x2), per wave 4x4 x mfma_f32_16x16x32_bf16
// per 32-k subtile (2 subtiles / K-step).
enum { EQKV, EPROJ, EFF1, EFF2, EFF2I };

template <int EPI>
__global__ __launch_bounds__(256, 2) void gemm_bt(
    const u16* __restrict__ A, const u16* __restrict__ Bt, int K, long lda,
    long ldb, const float* __restrict__ c0, const float* __restrict__ c1,
    const float* __restrict__ c2, const float* __restrict__ aux,
    float* __restrict__ fout, u16* __restrict__ o0, u16* __restrict__ o1,
    u16* __restrict__ o2, int ebase, long ldc) {
  __shared__ u16 As[8192], Bs[8192];  // 128 x 64 each (16 KB x2)
  long zc = 0;
  if constexpr (EPI == EFF2 || EPI == EFF2I) {  // K-split over grid.z
    const long z = blockIdx.z;
    A += z * (long)K;
    Bt += z * (long)K;
    fout += z * 4194304;  // per-z fp32 partial [4096][1024]
  }
  if constexpr (EPI == EFF1) {  // expert-batch over grid.z
    Bt += (long)blockIdx.z * 4194304;
    zc = (long)blockIdx.z * 4096;
  }
  const int tid = threadIdx.x;
  const int m0 = blockIdx.y * 128, n0 = blockIdx.x * 128;
  const int w = tid >> 6, l = tid & 63;
  const int wm = (w >> 1) * 64, wn = (w & 1) * 64;
  const int lr = l & 15, lh = l >> 4;
  f32x4 acc[4][4] = {};
  const u16* Ag = A + (long)(m0 + (tid >> 3)) * lda + (tid & 7) * 8;
  const u16* Bg = Bt + (long)(n0 + (tid >> 3)) * ldb + (tid & 7) * 8;
  for (int kt = 0; kt < K; kt += 64) {
    __syncthreads();
    gload16(Ag, As + tid * 8);
    gload16(Ag + 32 * lda, As + tid * 8 + 2048);
    gload16(Ag + 64 * lda, As + tid * 8 + 4096);
    gload16(Ag + 96 * lda, As + tid * 8 + 6144);
    gload16(Bg, Bs + tid * 8);
    gload16(Bg + 32 * ldb, Bs + tid * 8 + 2048);
    gload16(Bg + 64 * ldb, Bs + tid * 8 + 4096);
    gload16(Bg + 96 * ldb, Bs + tid * 8 + 6144);
    Ag += 64; Bg += 64;
    __syncthreads();
#pragma unroll
    for (int kk = 0; kk < 2; kk++) {
      bf16x8 af[4], bfr[4];
#pragma unroll
      for (int i = 0; i < 4; i++)
        af[i] = *(const bf16x8*)&As[(wm + i * 16 + lr) * 64 + kk * 32 + lh * 8];
#pragma unroll
      for (int j = 0; j < 4; j++)
        bfr[j] = *(const bf16x8*)&Bs[(wn + j * 16 + lr) * 64 + kk * 32 + lh * 8];
#pragma unroll
      for (int i = 0; i < 4; i++)
#pragma unroll
        for (int j = 0; j < 4; j++)
          acc[i][j] = __builtin_amdgcn_mfma_f32_16x16x32_bf16(
              af[i], bfr[j], acc[i][j], 0, 0, 0);
    }
  }
  // epilogue: elem (i,j,r) -> row = m0+wm+i*16+lh*4+r, col = n0+wn+j*16+lr
#pragma unroll
  for (int j = 0; j < 4; j++) {
    const int col = n0 + wn + j * 16 + lr;
#pragma unroll
    for (int i = 0; i < 4; i++)
#pragma unroll
      for (int r = 0; r < 4; r++) {
        const int row = m0 + wm + i * 16 + lh * 4 + r;
        float v = acc[i][j][r];
        if constexpr (EPI == EQKV) {
          const int which = col >> 10, hd = col & 1023;
          const float vb =
              v + ((which == 0) ? c0 : (which == 1) ? c1 : c2)[hd];
          const int b = row >> 10, s = row & 1023;
          const int h = hd >> 6, d = hd & 63;
          const long bh = b * 16 + h;
          if (which == 0)
            o0[(bh * 1024 + s) * 64 + d] = f2b(vb * 0.125f);  // q pre-scaled
          else if (which == 1)
            o1[(bh * 1024 + s) * 64 + d] = f2b(vb);           // k
          else
            o2[bh * 65536 + (long)d * 1024 + s] = f2b(vb);    // v transposed
        } else if constexpr (EPI == EPROJ) {
          const long idx = (long)row * 1024 + col;
          fout[idx] = v + c0[col] + aux[idx];  // + bp + x residual
        } else if constexpr (EPI == EFF1) {
          const int e = ebase + blockIdx.z;
          const float t = v + c0[(long)e * 4096 + col];
          const float rl = t > 0.f ? t : 0.f;
          const float pw = aux[(long)row * 8 + e];  // router prob folded in
          o0[(long)row * ldc + zc + col] = f2b(rl * pw);
        } else {  // EFF2 (accumulate) / EFF2I (init)
          const long idx = (long)row * 1024 + col;
          if constexpr (EPI == EFF2I)
            fout[idx] = v;
          else
            fout[idx] = fout[idx] + v;
        }
      }
  }
}

// ---------------------------------------------------------------- attention
// Swapped-operand flash attn: grid (S/64, B*H), 4 waves, 16 q-rows per wave,
// one q per lane (q = q0 + (lane&15)). QK^T swapped -> S^T (t in regs),
// PV swapped -> O^T. No LDS; P^T fragment built via 16 parallel shuffles.
__global__ __launch_bounds__(256) void attn_fwd(const u16* __restrict__ Qb,
                                                const u16* __restrict__ Kb,
                                                const u16* __restrict__ Vt,
                                                u16* __restrict__ Cat) {
  const int tid = threadIdx.x;
  const int w = tid >> 6, l = tid & 63;
  const int lr = l & 15, lh = l >> 4;
  const int bh = blockIdx.y;
  const int q0 = blockIdx.x * 64 + w * 16;
  const u16* Qp = Qb + (long)bh * 65536;
  const u16* Kp = Kb + (long)bh * 65536;
  const u16* Vp = Vt + (long)bh * 65536;  // [64 d][1024 t]
  // Q as B-operand: lane holds col q=lr, k-span lh*8 over d
  const bf16x8 qf0 = *(const bf16x8*)&Qp[(q0 + lr) * 64 + lh * 8];
  const bf16x8 qf1 = *(const bf16x8*)&Qp[(q0 + lr) * 64 + 32 + lh * 8];
  const int q = q0 + lr;
  f32x4 o[4] = {};                 // O^T: d = dt*16 + lh*4 + r, this lane's q
  float m = -1e30f, ssum = 0.f;    // per-q running max / lane-partial sum
  const int hi = lh >> 1;
  const int s0 = ((lh & 1) * 2) * 16 + lr;
  const int s1 = ((lh & 1) * 2 + 1) * 16 + lr;
  const int nkt = q0 / 32 + 1;
  for (int kt = 0; kt < nkt; kt++) {
    const int t0 = kt * 32;
    f32x4 sc[2];  // S^T: t = t0 + ts*16 + lh*4 + r, col q
#pragma unroll
    for (int ts = 0; ts < 2; ts++) {
      const bf16x8 kf0 = *(const bf16x8*)&Kp[(t0 + ts * 16 + lr) * 64 + lh * 8];
      const bf16x8 kf1 =
          *(const bf16x8*)&Kp[(t0 + ts * 16 + lr) * 64 + 32 + lh * 8];
      f32x4 c = {};
      c = __builtin_amdgcn_mfma_f32_16x16x32_bf16(kf0, qf0, c, 0, 0, 0);
      c = __builtin_amdgcn_mfma_f32_16x16x32_bf16(kf1, qf1, c, 0, 0, 0);
      sc[ts] = c;
    }
#pragma unroll
    for (int ts = 0; ts < 2; ts++)
#pragma unroll
      for (int r = 0; r < 4; r++)
        if (t0 + ts * 16 + lh * 4 + r > q) sc[ts][r] = -1e30f;  // causal
    // row-max over t: 7 in-lane + 2 cross-lane (lanes lr, lr+16, +32, +48)
    float mt = fmaxf(fmaxf(fmaxf(sc[0][0], sc[0][1]), fmaxf(sc[0][2], sc[0][3])),
                     fmaxf(fmaxf(sc[1][0], sc[1][1]), fmaxf(sc[1][2], sc[1][3])));
    mt = fmaxf(mt, __shfl_xor(mt, 16));
    mt = fmaxf(mt, __shfl_xor(mt, 32));
    const float mnew = fmaxf(m, mt);
    const float scl = __expf(m - mnew);
    m = mnew;
    float p0[4], p1[4], ps = 0.f;
#pragma unroll
    for (int r = 0; r < 4; r++) {
      p0[r] = __expf(sc[0][r] - mnew);
      p1[r] = __expf(sc[1][r] - mnew);
      ps += p0[r] + p1[r];
    }
    ssum = ssum * scl + ps;  // lane-partial; reduced once after the loop
    // build P^T B-fragment: pb[j] = P[t0+lh*8+j][q]
    u16 pb[8];
#pragma unroll
    for (int r = 0; r < 4; r++) {
      const float a0 = __shfl(p0[r], s0), b0 = __shfl(p1[r], s0);
      const float a1 = __shfl(p0[r], s1), b1 = __shfl(p1[r], s1);
      pb[r] = f2b(hi ? b0 : a0);
      pb[r + 4] = f2b(hi ? b1 : a1);
    }
#pragma unroll
    for (int dt = 0; dt < 4; dt++)
#pragma unroll
      for (int r = 0; r < 4; r++) o[dt][r] *= scl;
    const bf16x8 pf = *(const bf16x8*)pb;
    __builtin_amdgcn_s_setprio(1);
#pragma unroll
    for (int dt = 0; dt < 4; dt++) {
      const bf16x8 vf =
          *(const bf16x8*)&Vp[(dt * 16 + lr) * 1024 + t0 + lh * 8];
      o[dt] = __builtin_amdgcn_mfma_f32_16x16x32_bf16(vf, pf, o[dt], 0, 0, 0);
    }
    __builtin_amdgcn_s_setprio(0);
  }
  ssum += __shfl_xor(ssum, 16);
  ssum += __shfl_xor(ssum, 32);
  const float inv = 1.f / ssum;
  const int b = bh >> 4, h = bh & 15;
#pragma unroll
  for (int dt = 0; dt < 4; dt++) {
    ushort4 st;
    st.x = f2b(o[dt][0] * inv);
    st.y = f2b(o[dt][1] * inv);
    st.z = f2b(o[dt][2] * inv);
    st.w = f2b(o[dt][3] * inv);
    *(ushort4*)&Cat[((long)(b * 1024 + q)) * 1024 + h * 64 + dt * 16 + lh * 4] =
        st;
  }
}

// ---------------------------------------------------------------- LN kernels
DEV float wred(float v) {
#pragma unroll
  for (int d = 1; d < 64; d <<= 1) v += __shfl_xor(v, d);
  return v;
}

__global__ __launch_bounds__(256) void ln1_router(
    const float* __restrict__ in, const float* __restrict__ g,
    const float* __restrict__ bb, const float* __restrict__ wr,
    const float* __restrict__ br, u16* __restrict__ h,
    float* __restrict__ probs) {
  __shared__ float rs[4], rs2[4], rp[4][8];
  const int row = blockIdx.x, t = threadIdx.x;
  const int w = t >> 6, l = t & 63;
  const float4 v = *(const float4*)&in[(long)row * 1024 + t * 4];
  float s = v.x + v.y + v.z + v.w;
  float s2 = v.x * v.x + v.y * v.y + v.z * v.z + v.w * v.w;
  s = wred(s);
  s2 = wred(s2);
  if (l == 0) { rs[w] = s; rs2[w] = s2; }
  __syncthreads();
  const float S = rs[0] + rs[1] + rs[2] + rs[3];
  const float S2 = rs2[0] + rs2[1] + rs2[2] + rs2[3];
  const float mean = S * (1.f / 1024.f);
  const float var = S2 * (1.f / 1024.f) - mean * mean;
  const float rr = rsqrtf(var + 1e-5f);
  const float4 gv = *(const float4*)&g[t * 4];
  const float4 bv = *(const float4*)&bb[t * 4];
  float hv[4];
  hv[0] = (v.x - mean) * rr * gv.x + bv.x;
  hv[1] = (v.y - mean) * rr * gv.y + bv.y;
  hv[2] = (v.z - mean) * rr * gv.z + bv.z;
  hv[3] = (v.w - mean) * rr * gv.w + bv.w;
  ushort4 hb;
  hb.x = f2b(hv[0]); hb.y = f2b(hv[1]); hb.z = f2b(hv[2]); hb.w = f2b(hv[3]);
  *(ushort4*)&h[(long)row * 1024 + t * 4] = hb;
  float pr[8] = {};
  const float* wrp = wr + t * 4 * 8;
#pragma unroll
  for (int e = 0; e < 4; e++)
#pragma unroll
    for (int j = 0; j < 8; j++) pr[j] += hv[e] * wrp[e * 8 + j];
#pragma unroll
  for (int j = 0; j < 8; j++) pr[j] = wred(pr[j]);
  if (l == 0)
#pragma unroll
    for (int j = 0; j < 8; j++) rp[w][j] = pr[j];
  __syncthreads();
  if (t == 0) {
    float lg[8], mx = -1e30f;
#pragma unroll
    for (int j = 0; j < 8; j++) {
      lg[j] = rp[0][j] + rp[1][j] + rp[2][j] + rp[3][j] + br[j];
      mx = fmaxf(mx, lg[j]);
    }
    float sm = 0.f;
#pragma unroll
    for (int j = 0; j < 8; j++) {
      lg[j] = __expf(lg[j] - mx);
      sm += lg[j];
    }
    const float inv = 1.f / sm;
#pragma unroll
    for (int j = 0; j < 8; j++) probs[row * 8 + j] = lg[j] * inv;
  }
}

// out = LN( sum_z moe_z + x + sum_n probs[n]*b2[n] )
__global__ __launch_bounds__(256) void ln2_kernel(
    const float* __restrict__ moe, const float* __restrict__ xres,
    const float* __restrict__ probs, const float* __restrict__ b2,
    const float* __restrict__ g, const float* __restrict__ bb,
    float* __restrict__ out, int np) {
  __shared__ float rs[4], rs2[4];
  const int row = blockIdx.x, t = threadIdx.x;
  const int w = t >> 6, l = t & 63;
  const long base = (long)row * 1024 + t * 4;
  float4 v = *(const float4*)&xres[base];
  for (int z = 0; z < np; z++) {
    const float4 a = *(const float4*)&moe[(long)z * 4194304 + base];
    v.x += a.x; v.y += a.y; v.z += a.z; v.w += a.w;
  }
#pragma unroll
  for (int n = 0; n < 8; n++) {
    const float pw = probs[(long)row * 8 + n];
    const float4 bv4 = *(const float4*)&b2[n * 1024 + t * 4];
    v.x += pw * bv4.x; v.y += pw * bv4.y;
    v.z += pw * bv4.z; v.w += pw * bv4.w;
  }
  float s = v.x + v.y + v.z + v.w;
  float s2 = v.x * v.x + v.y * v.y + v.z * v.z + v.w * v.w;
  s = wred(s);
  s2 = wred(s2);
  if (l == 0) { rs[w] = s; rs2[w] = s2; }
  __syncthreads();
  const float S = rs[0] + rs[1] + rs[2] + rs[3];
  const float S2 = rs2[0] + rs2[1] + rs2[2] + rs2[3];
  const float mean = S * (1.f / 1024.f);
  const float var = S2 * (1.f / 1024.f) - mean * mean;
  const float rr = rsqrtf(var + 1e-5f);
  const float4 gv = *(const float4*)&g[t * 4];
  const float4 bv = *(const float4*)&bb[t * 4];
  float4 oo;
  oo.x = (v.x - mean) * rr * gv.x + bv.x;
  oo.y = (v.y - mean) * rr * gv.y + bv.y;
  oo.z = (v.z - mean) * rr * gv.z + bv.z;
  oo.w = (v.w - mean) * rr * gv.w + bv.w;
  *(float4*)&out[base] = oo;
}

// ---------------------------------------------------------------- launch
extern "C" void kernel_launch(void* const* d_in, const int* in_sizes, int n_in,
                              void* d_out, int out_size, void* d_ws,
                              size_t ws_size, hipStream_t stream) {
  const float* x = (const float*)d_in[0];
  const float* wq = (const float*)d_in[1];
  const float* bq = (const float*)d_in[2];
  const float* wk = (const float*)d_in[3];
  const float* bk = (const float*)d_in[4];
  const float* wv = (const float*)d_in[5];
  const float* bv = (const float*)d_in[6];
  const float* wp = (const float*)d_in[7];
  const float* bp = (const float*)d_in[8];
  const float* g1 = (const float*)d_in[9];
  const float* be1 = (const float*)d_in[10];
  const float* g2 = (const float*)d_in[11];
  const float* be2 = (const float*)d_in[12];
  const float* wr = (const float*)d_in[13];
  const float* br = (const float*)d_in[14];
  const float* w1 = (const float*)d_in[15];
  const float* b1 = (const float*)d_in[16];
  const float* w2 = (const float*)d_in[17];
  const float* b2 = (const float*)d_in[18];
  float* out = (float*)d_out;

  char* p = (char*)d_ws;
  auto alloc = [&](size_t bytes) {
    char* r = p;
    p += (bytes + 255) & ~(size_t)255;
    return r;
  };
  // Layout (seq path footprint == proven 232 MB; fast path reuses dead
  // regions for moe slices 2,3 and for the 256 MB all-expert mid).
  u16* w1t = (u16*)alloc(67108864);    // [8][4096 f][1024 e]  B^T per expert
  u16* w2t2 = (u16*)alloc(67108864);   // [1024 e][8*4096]  (k = n*4096+f)
  u16* hb = (u16*)alloc(8388608);      // LN1 out bf16 [4096][1024]
  float* probs = (float*)alloc(131072);
  float* moe = (float*)alloc(33554432);   // fp32 partial slices 0,1
  float* resid1 = (float*)alloc(16777216);  // == moe slice 2 (fast path)
  u16* xb = (u16*)alloc(8388608);           // == moe slice 3 (fast path)
  u16* wqkvt = (u16*)alloc(6291456);
  u16* wpt = (u16*)alloc(2097152);
  u16* qb = (u16*)alloc(8388608);      // fast-path mid starts here (256 MB)
  u16* kb = (u16*)alloc(8388608);
  u16* vt = (u16*)alloc(8388608);
  u16* cat = (u16*)alloc(8388608);
  // fast path needs: offset(qb) + 256 MB = ~456.2 MB
  const size_t need_fast = (size_t)((char*)qb - (char*)d_ws) + (size_t)268435456;
  const bool fast = ws_size >= need_fast;

  const dim3 tb(32, 8);
  cvt_bf16<<<4096, 256, 0, stream>>>(x, xb);
  tpose_bf16<<<dim3(2, 32, 16), tb, 0, stream>>>(wq, wqkvt, 1024, 64, 65536, 65536, 1024);
  tpose_bf16<<<dim3(2, 32, 16), tb, 0, stream>>>(wk, wqkvt + 1048576, 1024, 64, 65536, 65536, 1024);
  tpose_bf16<<<dim3(2, 32, 16), tb, 0, stream>>>(wv, wqkvt + 2097152, 1024, 64, 65536, 65536, 1024);
  tpose_bf16<<<dim3(32, 32, 1), tb, 0, stream>>>(wp, wpt, 1024, 1024, 0, 0, 1024);
  tpose_bf16<<<dim3(128, 32, 8), tb, 0, stream>>>(w1, w1t, 1024, 4096, 4194304, 4194304, 1024);
  tpose_bf16<<<dim3(32, 128, 8), tb, 0, stream>>>(w2, w2t2, 4096, 1024, 4194304, 4096, 32768);

  gemm_bt<EQKV><<<dim3(24, 32), 256, 0, stream>>>(
      xb, wqkvt, 1024, 1024, 1024, bq, bk, bv, nullptr, nullptr, qb, kb, vt,
      0, 0);
  attn_fwd<<<dim3(16, 64), 256, 0, stream>>>(qb, kb, vt, cat);
  gemm_bt<EPROJ><<<dim3(8, 32), 256, 0, stream>>>(
      cat, wpt, 1024, 1024, 1024, bp, nullptr, nullptr, x, resid1, nullptr,
      nullptr, nullptr, 0, 0);
  ln1_router<<<4096, 256, 0, stream>>>(resid1, g1, be1, wr, br, hb, probs);

  if (fast) {
    u16* mid = qb;  // [4096][8*4096] bf16, aliases qb..cat + fresh tail
    gemm_bt<EFF1><<<dim3(32, 32, 8), 256, 0, stream>>>(
        hb, w1t, 1024, 1024, 1024, b1, nullptr, nullptr, probs, nullptr, mid,
        nullptr, nullptr, 0, 32768);
    gemm_bt<EFF2I><<<dim3(8, 32, 4), 256, 0, stream>>>(
        mid, w2t2, 8192, 32768, 32768, nullptr, nullptr, nullptr, nullptr,
        moe, nullptr, nullptr, nullptr, 0, 0);
    ln2_kernel<<<4096, 256, 0, stream>>>(moe, x, probs, b2, g2, be2, out, 4);
  } else {
    u16* mid = qb;  // [4096][4096] bf16 per expert, reused (32 MB)
    for (int n = 0; n < 8; n++) {
      gemm_bt<EFF1><<<dim3(32, 32, 1), 256, 0, stream>>>(
          hb, w1t + (long)n * 4194304, 1024, 1024, 1024, b1, nullptr, nullptr,
          probs, nullptr, mid, nullptr, nullptr, n, 4096);
      if (n == 0)
        gemm_bt<EFF2I><<<dim3(8, 32, 2), 256, 0, stream>>>(
            mid, w2t2 + (long)n * 4096, 2048, 4096, 32768, nullptr, nullptr,
            nullptr, nullptr, moe, nullptr, nullptr, nullptr, 0, 0);
      else
        gemm_bt<EFF2><<<dim3(8, 32, 2), 256, 0, stream>>>(
            mid, w2t2 + (long)n * 4096, 2048, 4096, 32768, nullptr, nullptr,
            nullptr, nullptr, moe, nullptr, nullptr, nullptr, 0, 0);
    }
    ln2_kernel<<<4096, 256, 0, stream>>>(moe, x, probs, b2, g2, be2, out, 2);
  }
}

// Round 5
// 1331.893 us; speedup vs baseline: 1.2359x; 1.1450x over previous
//
#include <hip/hip_runtime.h>
#include <hip/hip_bf16.h>

typedef unsigned short u16;
typedef unsigned int u32;
typedef __attribute__((ext_vector_type(8))) short bf16x8;
typedef __attribute__((ext_vector_type(4))) float f32x4;

#define DEV static __device__ __forceinline__

// fp32 -> bf16, round-to-nearest-even
DEV u16 f2b(float f) {
  union { float f; u32 u; } v; v.f = f;
  return (u16)((v.u + 0x7fffu + ((v.u >> 16) & 1u)) >> 16);
}

// async global->LDS, 16B per lane. LDS dest linear in lane order (wave-uniform
// base + lane*16 — tid*8 u16 satisfies this).
DEV void gload16(const void* g, void* l) {
  __builtin_amdgcn_global_load_lds(
      (const __attribute__((address_space(1))) u32*)g,
      (__attribute__((address_space(3))) u32*)l, 16, 0, 0);
}

// ---------------------------------------------------------------- converts
__global__ __launch_bounds__(256) void cvt_bf16(const float* __restrict__ s,
                                                u16* __restrict__ d) {
  const long i = ((long)blockIdx.x * 256 + threadIdx.x) * 4;
  const float4 v = *(const float4*)&s[i];
  ushort4 o;
  o.x = f2b(v.x); o.y = f2b(v.y); o.z = f2b(v.z); o.w = f2b(v.w);
  *(ushort4*)&d[i] = o;
}

// src [bz][R][C] fp32 -> dst: elem [c][r] stored at dst + bz*dStride + c*ldd + r
__global__ __launch_bounds__(256) void tpose_bf16(const float* __restrict__ src,
                                                  u16* __restrict__ dst, int R,
                                                  int C, long sStride,
                                                  long dStride, long ldd) {
  __shared__ float tl[32][33];
  const float* s = src + (long)blockIdx.z * sStride;
  u16* d = dst + (long)blockIdx.z * dStride;
  const int c0 = blockIdx.x * 32, r0 = blockIdx.y * 32;
  const int tx = threadIdx.x, ty = threadIdx.y;  // (32,8)
#pragma unroll
  for (int k = 0; k < 4; k++)
    tl[ty + k * 8][tx] = s[(long)(r0 + ty + k * 8) * C + c0 + tx];
  __syncthreads();
#pragma unroll
  for (int k = 0; k < 4; k++)
    d[(long)(c0 + ty + k * 8) * ldd + r0 + tx] = f2b(tl[tx][ty + k * 8]);
}

// ---------------------------------------------------------------- GEMM
// C[row][col] = sum_k A[row][k] * Bt[col][k]   (A row-major, B^T row-major)
// 128x128 tile, BK=64, 4 waves (2x2), per wave 4x4 x mfma_f32_16x16x32_bf16
// per 32-k subtile (2 subtiles / K-step).
// LDS tiles use a T2 XOR swizzle (u16 col ^= (row&7)<<3) to spread
// ds_read_b128 bank bases; gload_lds dest stays LINEAR, the swizzle is
// applied by pre-swizzling the per-lane GLOBAL source column (rule 21).
enum { EQKV, EPROJ, EFF1, EFF2, EFF2I };

template <int EPI>
__global__ __launch_bounds__(256, 4) void gemm_bt(
    const u16* __restrict__ A, const u16* __restrict__ Bt, int K, long lda,
    long ldb, const float* __restrict__ c0, const float* __restrict__ c1,
    const float* __restrict__ c2, const float* __restrict__ aux,
    float* __restrict__ fout, u16* __restrict__ o0, u16* __restrict__ o1,
    u16* __restrict__ o2, int ebase, long ldc) {
  __shared__ u16 As[8192], Bs[8192];  // 128 x 64 each (16 KB x2)
  long zc = 0;
  if constexpr (EPI == EFF2 || EPI == EFF2I) {  // K-split over grid.z
    const long z = blockIdx.z;
    A += z * (long)K;
    Bt += z * (long)K;
    fout += z * 4194304;  // per-z fp32 partial [4096][1024]
  }
  if constexpr (EPI == EFF1) {  // expert-batch over grid.z
    Bt += (long)blockIdx.z * 4194304;
    zc = (long)blockIdx.z * 4096;
  }
  const int tid = threadIdx.x;
  const int m0 = blockIdx.y * 128, n0 = blockIdx.x * 128;
  const int w = tid >> 6, l = tid & 63;
  const int wm = (w >> 1) * 64, wn = (w & 1) * 64;
  const int lr = l & 15, lh = l >> 4;
  f32x4 acc[4][4] = {};
  // swizzled source column: semantic col ((tid&7)*8) stored at LDS col
  // ((tid&7)*8)^((row&7)<<3); row&7 == (tid>>3)&7 for all 4 row-quarters.
  const int scol = ((tid & 7) * 8) ^ (((tid >> 3) & 7) << 3);
  const u16* Ag = A + (long)(m0 + (tid >> 3)) * lda + scol;
  const u16* Bg = Bt + (long)(n0 + (tid >> 3)) * ldb + scol;
  for (int kt = 0; kt < K; kt += 64) {
    __syncthreads();
    gload16(Ag, As + tid * 8);
    gload16(Ag + 32 * lda, As + tid * 8 + 2048);
    gload16(Ag + 64 * lda, As + tid * 8 + 4096);
    gload16(Ag + 96 * lda, As + tid * 8 + 6144);
    gload16(Bg, Bs + tid * 8);
    gload16(Bg + 32 * ldb, Bs + tid * 8 + 2048);
    gload16(Bg + 64 * ldb, Bs + tid * 8 + 4096);
    gload16(Bg + 96 * ldb, Bs + tid * 8 + 6144);
    Ag += 64; Bg += 64;
    __syncthreads();
#pragma unroll
    for (int kk = 0; kk < 2; kk++) {
      const int cbase = kk * 32 + lh * 8;
      const int cswz = cbase ^ ((lr & 7) << 3);  // (row&7)==(lr&7) here
      bf16x8 af[4], bfr[4];
#pragma unroll
      for (int i = 0; i < 4; i++)
        af[i] = *(const bf16x8*)&As[(wm + i * 16 + lr) * 64 + cswz];
#pragma unroll
      for (int j = 0; j < 4; j++)
        bfr[j] = *(const bf16x8*)&Bs[(wn + j * 16 + lr) * 64 + cswz];
#pragma unroll
      for (int i = 0; i < 4; i++)
#pragma unroll
        for (int j = 0; j < 4; j++)
          acc[i][j] = __builtin_amdgcn_mfma_f32_16x16x32_bf16(
              af[i], bfr[j], acc[i][j], 0, 0, 0);
    }
  }
  // epilogue: elem (i,j,r) -> row = m0+wm+i*16+lh*4+r, col = n0+wn+j*16+lr
#pragma unroll
  for (int j = 0; j < 4; j++) {
    const int col = n0 + wn + j * 16 + lr;
#pragma unroll
    for (int i = 0; i < 4; i++)
#pragma unroll
      for (int r = 0; r < 4; r++) {
        const int row = m0 + wm + i * 16 + lh * 4 + r;
        float v = acc[i][j][r];
        if constexpr (EPI == EQKV) {
          const int which = col >> 10, hd = col & 1023;
          const float vb =
              v + ((which == 0) ? c0 : (which == 1) ? c1 : c2)[hd];
          const int b = row >> 10, s = row & 1023;
          const int h = hd >> 6, d = hd & 63;
          const long bh = b * 16 + h;
          if (which == 0)
            o0[(bh * 1024 + s) * 64 + d] = f2b(vb * 0.125f);  // q pre-scaled
          else if (which == 1)
            o1[(bh * 1024 + s) * 64 + d] = f2b(vb);           // k
          else
            o2[bh * 65536 + (long)d * 1024 + s] = f2b(vb);    // v transposed
        } else if constexpr (EPI == EPROJ) {
          const long idx = (long)row * 1024 + col;
          fout[idx] = v + c0[col] + aux[idx];  // + bp + x residual
        } else if constexpr (EPI == EFF1) {
          const int e = ebase + blockIdx.z;
          const float t = v + c0[(long)e * 4096 + col];
          const float rl = t > 0.f ? t : 0.f;
          const float pw = aux[(long)row * 8 + e];  // router prob folded in
          o0[(long)row * ldc + zc + col] = f2b(rl * pw);
        } else {  // EFF2 (accumulate) / EFF2I (init)
          const long idx = (long)row * 1024 + col;
          if constexpr (EPI == EFF2I)
            fout[idx] = v;
          else
            fout[idx] = fout[idx] + v;
        }
      }
  }
}

// ---------------------------------------------------------------- attention
// Swapped-operand flash attn: grid (S/64, B*H), 4 waves, 16 q-rows per wave,
// one q per lane (q = q0 + (lane&15)). QK^T swapped -> S^T (t in regs),
// PV swapped -> O^T. No LDS; P^T fragment built via 16 parallel shuffles.
__global__ __launch_bounds__(256) void attn_fwd(const u16* __restrict__ Qb,
                                                const u16* __restrict__ Kb,
                                                const u16* __restrict__ Vt,
                                                u16* __restrict__ Cat) {
  const int tid = threadIdx.x;
  const int w = tid >> 6, l = tid & 63;
  const int lr = l & 15, lh = l >> 4;
  const int bh = blockIdx.y;
  const int q0 = blockIdx.x * 64 + w * 16;
  const u16* Qp = Qb + (long)bh * 65536;
  const u16* Kp = Kb + (long)bh * 65536;
  const u16* Vp = Vt + (long)bh * 65536;  // [64 d][1024 t]
  // Q as B-operand: lane holds col q=lr, k-span lh*8 over d
  const bf16x8 qf0 = *(const bf16x8*)&Qp[(q0 + lr) * 64 + lh * 8];
  const bf16x8 qf1 = *(const bf16x8*)&Qp[(q0 + lr) * 64 + 32 + lh * 8];
  const int q = q0 + lr;
  f32x4 o[4] = {};                 // O^T: d = dt*16 + lh*4 + r, this lane's q
  float m = -1e30f, ssum = 0.f;    // per-q running max / lane-partial sum
  const int hi = lh >> 1;
  const int s0 = ((lh & 1) * 2) * 16 + lr;
  const int s1 = ((lh & 1) * 2 + 1) * 16 + lr;
  const int nkt = q0 / 32 + 1;
  for (int kt = 0; kt < nkt; kt++) {
    const int t0 = kt * 32;
    f32x4 sc[2];  // S^T: t = t0 + ts*16 + lh*4 + r, col q
#pragma unroll
    for (int ts = 0; ts < 2; ts++) {
      const bf16x8 kf0 = *(const bf16x8*)&Kp[(t0 + ts * 16 + lr) * 64 + lh * 8];
      const bf16x8 kf1 =
          *(const bf16x8*)&Kp[(t0 + ts * 16 + lr) * 64 + 32 + lh * 8];
      f32x4 c = {};
      c = __builtin_amdgcn_mfma_f32_16x16x32_bf16(kf0, qf0, c, 0, 0, 0);
      c = __builtin_amdgcn_mfma_f32_16x16x32_bf16(kf1, qf1, c, 0, 0, 0);
      sc[ts] = c;
    }
#pragma unroll
    for (int ts = 0; ts < 2; ts++)
#pragma unroll
      for (int r = 0; r < 4; r++)
        if (t0 + ts * 16 + lh * 4 + r > q) sc[ts][r] = -1e30f;  // causal
    // row-max over t: 7 in-lane + 2 cross-lane (lanes lr, lr+16, +32, +48)
    float mt = fmaxf(fmaxf(fmaxf(sc[0][0], sc[0][1]), fmaxf(sc[0][2], sc[0][3])),
                     fmaxf(fmaxf(sc[1][0], sc[1][1]), fmaxf(sc[1][2], sc[1][3])));
    mt = fmaxf(mt, __shfl_xor(mt, 16));
    mt = fmaxf(mt, __shfl_xor(mt, 32));
    const float mnew = fmaxf(m, mt);
    const float scl = __expf(m - mnew);
    m = mnew;
    float p0[4], p1[4], ps = 0.f;
#pragma unroll
    for (int r = 0; r < 4; r++) {
      p0[r] = __expf(sc[0][r] - mnew);
      p1[r] = __expf(sc[1][r] - mnew);
      ps += p0[r] + p1[r];
    }
    ssum = ssum * scl + ps;  // lane-partial; reduced once after the loop
    // build P^T B-fragment: pb[j] = P[t0+lh*8+j][q]
    u16 pb[8];
#pragma unroll
    for (int r = 0; r < 4; r++) {
      const float a0 = __shfl(p0[r], s0), b0 = __shfl(p1[r], s0);
      const float a1 = __shfl(p0[r], s1), b1 = __shfl(p1[r], s1);
      pb[r] = f2b(hi ? b0 : a0);
      pb[r + 4] = f2b(hi ? b1 : a1);
    }
#pragma unroll
    for (int dt = 0; dt < 4; dt++)
#pragma unroll
      for (int r = 0; r < 4; r++) o[dt][r] *= scl;
    const bf16x8 pf = *(const bf16x8*)pb;
    __builtin_amdgcn_s_setprio(1);
#pragma unroll
    for (int dt = 0; dt < 4; dt++) {
      const bf16x8 vf =
          *(const bf16x8*)&Vp[(dt * 16 + lr) * 1024 + t0 + lh * 8];
      o[dt] = __builtin_amdgcn_mfma_f32_16x16x32_bf16(vf, pf, o[dt], 0, 0, 0);
    }
    __builtin_amdgcn_s_setprio(0);
  }
  ssum += __shfl_xor(ssum, 16);
  ssum += __shfl_xor(ssum, 32);
  const float inv = 1.f / ssum;
  const int b = bh >> 4, h = bh & 15;
#pragma unroll
  for (int dt = 0; dt < 4; dt++) {
    ushort4 st;
    st.x = f2b(o[dt][0] * inv);
    st.y = f2b(o[dt][1] * inv);
    st.z = f2b(o[dt][2] * inv);
    st.w = f2b(o[dt][3] * inv);
    *(ushort4*)&Cat[((long)(b * 1024 + q)) * 1024 + h * 64 + dt * 16 + lh * 4] =
        st;
  }
}

// ---------------------------------------------------------------- LN kernels
DEV float wred(float v) {
#pragma unroll
  for (int d = 1; d < 64; d <<= 1) v += __shfl_xor(v, d);
  return v;
}

__global__ __launch_bounds__(256) void ln1_router(
    const float* __restrict__ in, const float* __restrict__ g,
    const float* __restrict__ bb, const float* __restrict__ wr,
    const float* __restrict__ br, u16* __restrict__ h,
    float* __restrict__ probs) {
  __shared__ float rs[4], rs2[4], rp[4][8];
  const int row = blockIdx.x, t = threadIdx.x;
  const int w = t >> 6, l = t & 63;
  const float4 v = *(const float4*)&in[(long)row * 1024 + t * 4];
  float s = v.x + v.y + v.z + v.w;
  float s2 = v.x * v.x + v.y * v.y + v.z * v.z + v.w * v.w;
  s = wred(s);
  s2 = wred(s2);
  if (l == 0) { rs[w] = s; rs2[w] = s2; }
  __syncthreads();
  const float S = rs[0] + rs[1] + rs[2] + rs[3];
  const float S2 = rs2[0] + rs2[1] + rs2[2] + rs2[3];
  const float mean = S * (1.f / 1024.f);
  const float var = S2 * (1.f / 1024.f) - mean * mean;
  const float rr = rsqrtf(var + 1e-5f);
  const float4 gv = *(const float4*)&g[t * 4];
  const float4 bv = *(const float4*)&bb[t * 4];
  float hv[4];
  hv[0] = (v.x - mean) * rr * gv.x + bv.x;
  hv[1] = (v.y - mean) * rr * gv.y + bv.y;
  hv[2] = (v.z - mean) * rr * gv.z + bv.z;
  hv[3] = (v.w - mean) * rr * gv.w + bv.w;
  ushort4 hb;
  hb.x = f2b(hv[0]); hb.y = f2b(hv[1]); hb.z = f2b(hv[2]); hb.w = f2b(hv[3]);
  *(ushort4*)&h[(long)row * 1024 + t * 4] = hb;
  float pr[8] = {};
  const float* wrp = wr + t * 4 * 8;
#pragma unroll
  for (int e = 0; e < 4; e++)
#pragma unroll
    for (int j = 0; j < 8; j++) pr[j] += hv[e] * wrp[e * 8 + j];
#pragma unroll
  for (int j = 0; j < 8; j++) pr[j] = wred(pr[j]);
  if (l == 0)
#pragma unroll
    for (int j = 0; j < 8; j++) rp[w][j] = pr[j];
  __syncthreads();
  if (t == 0) {
    float lg[8], mx = -1e30f;
#pragma unroll
    for (int j = 0; j < 8; j++) {
      lg[j] = rp[0][j] + rp[1][j] + rp[2][j] + rp[3][j] + br[j];
      mx = fmaxf(mx, lg[j]);
    }
    float sm = 0.f;
#pragma unroll
    for (int j = 0; j < 8; j++) {
      lg[j] = __expf(lg[j] - mx);
      sm += lg[j];
    }
    const float inv = 1.f / sm;
#pragma unroll
    for (int j = 0; j < 8; j++) probs[row * 8 + j] = lg[j] * inv;
  }
}

// out = LN( sum_z moe_z + x + sum_n probs[n]*b2[n] )
__global__ __launch_bounds__(256) void ln2_kernel(
    const float* __restrict__ moe, const float* __restrict__ xres,
    const float* __restrict__ probs, const float* __restrict__ b2,
    const float* __restrict__ g, const float* __restrict__ bb,
    float* __restrict__ out, int np) {
  __shared__ float rs[4], rs2[4];
  const int row = blockIdx.x, t = threadIdx.x;
  const int w = t >> 6, l = t & 63;
  const long base = (long)row * 1024 + t * 4;
  float4 v = *(const float4*)&xres[base];
  for (int z = 0; z < np; z++) {
    const float4 a = *(const float4*)&moe[(long)z * 4194304 + base];
    v.x += a.x; v.y += a.y; v.z += a.z; v.w += a.w;
  }
#pragma unroll
  for (int n = 0; n < 8; n++) {
    const float pw = probs[(long)row * 8 + n];
    const float4 bv4 = *(const float4*)&b2[n * 1024 + t * 4];
    v.x += pw * bv4.x; v.y += pw * bv4.y;
    v.z += pw * bv4.z; v.w += pw * bv4.w;
  }
  float s = v.x + v.y + v.z + v.w;
  float s2 = v.x * v.x + v.y * v.y + v.z * v.z + v.w * v.w;
  s = wred(s);
  s2 = wred(s2);
  if (l == 0) { rs[w] = s; rs2[w] = s2; }
  __syncthreads();
  const float S = rs[0] + rs[1] + rs[2] + rs[3];
  const float S2 = rs2[0] + rs2[1] + rs2[2] + rs2[3];
  const float mean = S * (1.f / 1024.f);
  const float var = S2 * (1.f / 1024.f) - mean * mean;
  const float rr = rsqrtf(var + 1e-5f);
  const float4 gv = *(const float4*)&g[t * 4];
  const float4 bv = *(const float4*)&bb[t * 4];
  float4 oo;
  oo.x = (v.x - mean) * rr * gv.x + bv.x;
  oo.y = (v.y - mean) * rr * gv.y + bv.y;
  oo.z = (v.z - mean) * rr * gv.z + bv.z;
  oo.w = (v.w - mean) * rr * gv.w + bv.w;
  *(float4*)&out[base] = oo;
}

// ---------------------------------------------------------------- launch
extern "C" void kernel_launch(void* const* d_in, const int* in_sizes, int n_in,
                              void* d_out, int out_size, void* d_ws,
                              size_t ws_size, hipStream_t stream) {
  const float* x = (const float*)d_in[0];
  const float* wq = (const float*)d_in[1];
  const float* bq = (const float*)d_in[2];
  const float* wk = (const float*)d_in[3];
  const float* bk = (const float*)d_in[4];
  const float* wv = (const float*)d_in[5];
  const float* bv = (const float*)d_in[6];
  const float* wp = (const float*)d_in[7];
  const float* bp = (const float*)d_in[8];
  const float* g1 = (const float*)d_in[9];
  const float* be1 = (const float*)d_in[10];
  const float* g2 = (const float*)d_in[11];
  const float* be2 = (const float*)d_in[12];
  const float* wr = (const float*)d_in[13];
  const float* br = (const float*)d_in[14];
  const float* w1 = (const float*)d_in[15];
  const float* b1 = (const float*)d_in[16];
  const float* w2 = (const float*)d_in[17];
  const float* b2 = (const float*)d_in[18];
  float* out = (float*)d_out;

  char* p = (char*)d_ws;
  auto alloc = [&](size_t bytes) {
    char* r = p;
    p += (bytes + 255) & ~(size_t)255;
    return r;
  };
  // Layout (seq path footprint == proven 232 MB; fast path reuses dead
  // regions for moe slices 2,3 and for the 256 MB all-expert mid).
  u16* w1t = (u16*)alloc(67108864);    // [8][4096 f][1024 e]  B^T per expert
  u16* w2t2 = (u16*)alloc(67108864);   // [1024 e][8*4096]  (k = n*4096+f)
  u16* hb = (u16*)alloc(8388608);      // LN1 out bf16 [4096][1024]
  float* probs = (float*)alloc(131072);
  float* moe = (float*)alloc(33554432);   // fp32 partial slices 0,1
  float* resid1 = (float*)alloc(16777216);  // == moe slice 2 (fast path)
  u16* xb = (u16*)alloc(8388608);           // == moe slice 3 (fast path)
  u16* wqkvt = (u16*)alloc(6291456);
  u16* wpt = (u16*)alloc(2097152);
  u16* qb = (u16*)alloc(8388608);      // fast-path mid starts here (256 MB)
  u16* kb = (u16*)alloc(8388608);
  u16* vt = (u16*)alloc(8388608);
  u16* cat = (u16*)alloc(8388608);
  // fast path needs: offset(qb) + 256 MB = ~456.2 MB
  const size_t need_fast = (size_t)((char*)qb - (char*)d_ws) + (size_t)268435456;
  const bool fast = ws_size >= need_fast;

  const dim3 tb(32, 8);
  cvt_bf16<<<4096, 256, 0, stream>>>(x, xb);
  tpose_bf16<<<dim3(2, 32, 16), tb, 0, stream>>>(wq, wqkvt, 1024, 64, 65536, 65536, 1024);
  tpose_bf16<<<dim3(2, 32, 16), tb, 0, stream>>>(wk, wqkvt + 1048576, 1024, 64, 65536, 65536, 1024);
  tpose_bf16<<<dim3(2, 32, 16), tb, 0, stream>>>(wv, wqkvt + 2097152, 1024, 64, 65536, 65536, 1024);
  tpose_bf16<<<dim3(32, 32, 1), tb, 0, stream>>>(wp, wpt, 1024, 1024, 0, 0, 1024);
  tpose_bf16<<<dim3(128, 32, 8), tb, 0, stream>>>(w1, w1t, 1024, 4096, 4194304, 4194304, 1024);
  tpose_bf16<<<dim3(32, 128, 8), tb, 0, stream>>>(w2, w2t2, 4096, 1024, 4194304, 4096, 32768);

  gemm_bt<EQKV><<<dim3(24, 32), 256, 0, stream>>>(
      xb, wqkvt, 1024, 1024, 1024, bq, bk, bv, nullptr, nullptr, qb, kb, vt,
      0, 0);
  attn_fwd<<<dim3(16, 64), 256, 0, stream>>>(qb, kb, vt, cat);
  gemm_bt<EPROJ><<<dim3(8, 32), 256, 0, stream>>>(
      cat, wpt, 1024, 1024, 1024, bp, nullptr, nullptr, x, resid1, nullptr,
      nullptr, nullptr, 0, 0);
  ln1_router<<<4096, 256, 0, stream>>>(resid1, g1, be1, wr, br, hb, probs);

  if (fast) {
    u16* mid = qb;  // [4096][8*4096] bf16, aliases qb..cat + fresh tail
    gemm_bt<EFF1><<<dim3(32, 32, 8), 256, 0, stream>>>(
        hb, w1t, 1024, 1024, 1024, b1, nullptr, nullptr, probs, nullptr, mid,
        nullptr, nullptr, 0, 32768);
    gemm_bt<EFF2I><<<dim3(8, 32, 4), 256, 0, stream>>>(
        mid, w2t2, 8192, 32768, 32768, nullptr, nullptr, nullptr, nullptr,
        moe, nullptr, nullptr, nullptr, 0, 0);
    ln2_kernel<<<4096, 256, 0, stream>>>(moe, x, probs, b2, g2, be2, out, 4);
  } else {
    u16* mid = qb;  // [4096][4096] bf16 per expert, reused (32 MB)
    for (int n = 0; n < 8; n++) {
      gemm_bt<EFF1><<<dim3(32, 32, 1), 256, 0, stream>>>(
          hb, w1t + (long)n * 4194304, 1024, 1024, 1024, b1, nullptr, nullptr,
          probs, nullptr, mid, nullptr, nullptr, n, 4096);
      if (n == 0)
        gemm_bt<EFF2I><<<dim3(8, 32, 2), 256, 0, stream>>>(
            mid, w2t2 + (long)n * 4096, 2048, 4096, 32768, nullptr, nullptr,
            nullptr, nullptr, moe, nullptr, nullptr, nullptr, 0, 0);
      else
        gemm_bt<EFF2><<<dim3(8, 32, 2), 256, 0, stream>>>(
            mid, w2t2 + (long)n * 4096, 2048, 4096, 32768, nullptr, nullptr,
            nullptr, nullptr, moe, nullptr, nullptr, nullptr, 0, 0);
    }
    ln2_kernel<<<4096, 256, 0, stream>>>(moe, x, probs, b2, g2, be2, out, 2);
  }
}